// Round 12
// baseline (616.179 us; speedup 1.0000x reference)
//
#include <hip/hip_runtime.h>
#include <hip/hip_bf16.h>
#include <hip/hip_cooperative_groups.h>
#include <math.h>

namespace cg = cooperative_groups;

#define F_IN   128
#define F_OUT  64
#define CHUNK  5120          // edges per hist/scatter chunk
#define MAXB   512           // max coarse buckets
#define PADSLACK 4096        // per-bucket padded-window slack
#define PART_GRID 512

typedef short bf16x8 __attribute__((ext_vector_type(8)));
typedef float f32x4  __attribute__((ext_vector_type(4)));
typedef float f32x2  __attribute__((ext_vector_type(2)));

__device__ __forceinline__ unsigned short f2bf(float f) {
    union { float f; unsigned int i; } c; c.f = f;
    unsigned int r = c.i + 0x7FFFu + ((c.i >> 16) & 1u);   // RNE
    return (unsigned short)(r >> 16);
}
__device__ __forceinline__ unsigned int pk2bf(float a, float b) {
    __hip_bfloat162 p = __float22bfloat162_rn(make_float2(a, b));  // v_cvt_pk_bf16_f32
    union { __hip_bfloat162 h; unsigned int u; } c; c.h = p; return c.u;
}
__device__ __forceinline__ float u_lo(unsigned int u) {
    union { unsigned int i; float f; } c; c.i = u << 16; return c.f;
}
__device__ __forceinline__ float u_hi(unsigned int u) {
    union { unsigned int i; float f; } c; c.i = u & 0xFFFF0000u; return c.f;
}

// shared memory union for k_part phases
union PartShared {
    int hist[MAXB];                                    // hist / scatter cursors
    int scan[512];                                     // scan1 / scan2
    struct { int hist[256]; int curs[256]; int se[2]; } sort;
};

__device__ __forceinline__ int exscan(const int* M, const int* tmp, const int* bsum, int i) {
    return tmp[i] - M[i] + bsum[i >> 8];
}

// ---- cooperative partition kernel: Wbf-convert + hist -> scan -> scatter -> sort ----
__global__ __launch_bounds__(256, 8) void k_part(
    const int* __restrict__ src, const int* __restrict__ dst, int E,
    int* __restrict__ M, int* __restrict__ tmp, int* __restrict__ bsum,
    int* __restrict__ offsetsP, int* __restrict__ deg,
    unsigned int* __restrict__ entries, unsigned int* __restrict__ srcsP,
    int N, int NBC, int NCH, int S, int NB1,
    const float* __restrict__ W, unsigned short* __restrict__ Wbf) {
    cg::grid_group grid = cg::this_grid();
    __shared__ PartShared su;
    const int tid = threadIdx.x;
    const int G = gridDim.x;

    // Phase 0: W -> bf16 (blocks 0..7, 2048 uint2 total)
    if (blockIdx.x < 8) {
        int idx = blockIdx.x * 256 + tid;   // 0..2047
        float4 v = ((const float4*)W)[idx];
        uint2 u = make_uint2(pk2bf(v.x, v.y), pk2bf(v.z, v.w));
        *(uint2*)&Wbf[idx * 4] = u;
    }

    // Phase 1: per-chunk coarse histogram -> M[bucket][chunk]
    for (int c = blockIdx.x; c < NCH; c += G) {
        for (int k = tid; k < MAXB; k += 256) su.hist[k] = 0;
        __syncthreads();
        int e0 = c * CHUNK, e1 = min(E, e0 + CHUNK);
        for (int e = e0 + tid; e < e1; e += 256)
            atomicAdd(&su.hist[dst[e] >> 8], 1);
        __syncthreads();
        for (int k = tid; k < NBC; k += 256)
            M[k * NCH + c] = su.hist[k];
        __syncthreads();
    }
    __threadfence();
    grid.sync();

    // Phase 2: scan1 — block-local inclusive scans of M -> tmp, block sums -> bsum
    for (int grp = blockIdx.x; grp < NB1; grp += G) {
        int i = grp * 256 + tid;
        int v = (i < S) ? M[i] : 0;
        su.scan[tid] = v;
        __syncthreads();
        for (int off = 1; off < 256; off <<= 1) {
            int t = (tid >= off) ? su.scan[tid - off] : 0;
            __syncthreads();
            su.scan[tid] += t;
            __syncthreads();
        }
        if (i < S) tmp[i] = su.scan[tid];
        if (tid == 255) bsum[grp] = su.scan[255];
        __syncthreads();
    }
    __threadfence();
    grid.sync();

    // Phase 3: scan2 — exclusive scan of bsum (block 0; 256 thr over <=512 vals)
    if (blockIdx.x == 0) {
        int v0 = (tid < NB1) ? bsum[tid] : 0;
        int v1 = (256 + tid < NB1) ? bsum[256 + tid] : 0;
        su.scan[tid] = v0;
        su.scan[256 + tid] = v1;
        __syncthreads();
        for (int off = 1; off < 512; off <<= 1) {
            int a = (tid >= off) ? su.scan[tid - off] : 0;
            int b = (256 + tid >= off) ? su.scan[256 + tid - off] : 0;
            __syncthreads();
            su.scan[tid] += a;
            su.scan[256 + tid] += b;
            __syncthreads();
        }
        if (tid < NB1) bsum[tid] = su.scan[tid] - v0;
        if (256 + tid < NB1) bsum[256 + tid] = su.scan[256 + tid] - v1;
    }
    __threadfence();
    grid.sync();

    // Phase 4: scatter packed entries (localdst<<24 | src) into coarse buckets
    for (int c = blockIdx.x; c < NCH; c += G) {
        for (int k = tid; k < NBC; k += 256)
            su.hist[k] = exscan(M, tmp, bsum, k * NCH + c);
        __syncthreads();
        int e0 = c * CHUNK, e1 = min(E, e0 + CHUNK);
        for (int e = e0 + tid; e < e1; e += 256) {
            int d = dst[e];
            int s = src[e];
            int p = atomicAdd(&su.hist[d >> 8], 1);
            entries[p] = ((unsigned int)(d & 255) << 24) | (unsigned int)s;
        }
        __syncthreads();
    }
    __threadfence();
    grid.sync();

    // Phase 5: per-bucket counting sort -> padded CSR of byte offsets
    for (int b = blockIdx.x; b < NBC; b += G) {
        if (tid == 0) {
            su.sort.se[0] = exscan(M, tmp, bsum, b * NCH);
            su.sort.se[1] = (b + 1 < NBC) ? exscan(M, tmp, bsum, (b + 1) * NCH) : E;
        }
        su.sort.hist[tid] = 0;
        __syncthreads();
        const int start = su.sort.se[0];
        const int end   = su.sort.se[1];
        const int startP = start + b * PADSLACK;

        for (int i = start + tid; i < end; i += 256)
            atomicAdd(&su.sort.hist[entries[i] >> 24], 1);
        __syncthreads();

        int cntv   = su.sort.hist[tid];
        int padded = (cntv + 15) & ~15;
        su.sort.curs[tid] = padded;
        __syncthreads();
        for (int off = 1; off < 256; off <<= 1) {
            int t = (tid >= off) ? su.sort.curs[tid - off] : 0;
            __syncthreads();
            su.sort.curs[tid] += t;
            __syncthreads();
        }
        int exclP = su.sort.curs[tid] - padded;
        int d = (b << 8) + tid;
        if (d < N) { offsetsP[d] = startP + exclP; deg[d] = cntv; }
        __syncthreads();
        su.sort.curs[tid] = startP + exclP;
        __syncthreads();

        for (int i = start + tid; i < end; i += 256) {
            unsigned int v = entries[i];
            int p = atomicAdd(&su.sort.curs[v >> 24], 1);
            srcsP[p] = (v & 0xFFFFFFu) << 7;
        }
        __syncthreads();

        int padEnd = startP + exclP + padded;
        unsigned int sent = ((unsigned int)N) << 7;
        for (int p = su.sort.curs[tid]; p < padEnd; ++p)
            srcsP[p] = sent;
        __syncthreads();
    }
}

// ---- MFMA GEMM (R10 LDS version): g = bf16((x @ W^T) * rsqrt(deg+1)); g[N]=0 ----
__global__ __launch_bounds__(256) void k_gemm(
    const float* __restrict__ x, const unsigned short* __restrict__ Wbf,
    const int* __restrict__ deg, unsigned short* __restrict__ g, int N) {
    __shared__ unsigned short xs[64 * F_IN];     // 16 KB
    __shared__ unsigned short Wsh[F_OUT * F_IN]; // 16 KB
    __shared__ float dinvs[64];

    const int tid  = threadIdx.x;
    const int row0 = blockIdx.x * 64;

    {   // W already bf16: straight copy (2048 uint2)
        const uint2* Wb = (const uint2*)Wbf;
        #pragma unroll
        for (int t = 0; t < 8; ++t) {
            int idx = t * 256 + tid;
            *(uint2*)&Wsh[idx * 4] = Wb[idx];
        }
    }
    {
        const float4* x4 = (const float4*)x;
        #pragma unroll
        for (int t = 0; t < 8; ++t) {
            int idx = t * 256 + tid;
            int r = idx >> 5;
            int grow = row0 + r;
            float4 v = make_float4(0.f, 0.f, 0.f, 0.f);
            if (grow < N) v = x4[(size_t)grow * 32 + (idx & 31)];
            uint2 u = make_uint2(pk2bf(v.x, v.y), pk2bf(v.z, v.w));
            *(uint2*)&xs[idx * 4] = u;
        }
    }
    if (tid < 64) {
        int grow = row0 + tid;
        float dv = 1.0f;
        if (grow < N) dv = rsqrtf((float)deg[grow] + 1.0f);
        dinvs[tid] = dv;
    }
    __syncthreads();

    const int lane = tid & 63;
    const int wave = tid >> 6;
    const int m = lane & 15;
    const int q = lane >> 4;
    const int r0 = wave * 16;

    bf16x8 a[4];
    #pragma unroll
    for (int ks = 0; ks < 4; ++ks)
        a[ks] = *(const bf16x8*)&xs[(r0 + m) * F_IN + ks * 32 + q * 8];

    f32x4 acc[4] = {{0,0,0,0},{0,0,0,0},{0,0,0,0},{0,0,0,0}};
    #pragma unroll
    for (int ct = 0; ct < 4; ++ct) {
        #pragma unroll
        for (int ks = 0; ks < 4; ++ks) {
            bf16x8 b = *(const bf16x8*)&Wsh[(ct * 16 + m) * F_IN + ks * 32 + q * 8];
            acc[ct] = __builtin_amdgcn_mfma_f32_16x16x32_bf16(a[ks], b, acc[ct], 0, 0, 0);
        }
    }

    float dv[4];
    #pragma unroll
    for (int reg = 0; reg < 4; ++reg)
        dv[reg] = dinvs[r0 + q * 4 + reg];
    #pragma unroll
    for (int ct = 0; ct < 4; ++ct) {
        #pragma unroll
        for (int reg = 0; reg < 4; ++reg) {
            int grow = row0 + r0 + q * 4 + reg;
            if (grow <= N)   // grow==N: zero sentinel row
                g[(size_t)grow * F_OUT + ct * 16 + m] = f2bf(acc[ct][reg] * dv[reg]);
        }
    }
}

// ---- pull aggregation + fused epilogue (unchanged R10) ----
__global__ __launch_bounds__(256) void k_pull(
    const unsigned short* __restrict__ g, const int* __restrict__ offsetsP,
    const int* __restrict__ deg, const unsigned int* __restrict__ srcsP,
    const float* __restrict__ b_conv, const float* __restrict__ W_lin,
    const float* __restrict__ b_lin, float* __restrict__ out, int N) {
    const int lane   = threadIdx.x & 63;
    const int grp    = lane >> 3;
    const int s      = lane & 7;
    const int wave   = (blockIdx.x * blockDim.x + threadIdx.x) >> 6;
    const int nwaves = (gridDim.x * blockDim.x) >> 6;

    const float2* b2 = (const float2*)b_conv;
    const float2* w2 = (const float2*)W_lin;
    f32x2 bb[4], wl[4];
    #pragma unroll
    for (int j = 0; j < 4; ++j) {
        float2 tb = b2[s * 4 + j]; bb[j] = (f32x2){tb.x, tb.y};
        float2 tw = w2[s * 4 + j]; wl[j] = (f32x2){tw.x, tw.y};
    }
    const float bl = b_lin[0];
    const float selfm = (grp == 0) ? 1.0f : 0.0f;
    const f32x2 selfv = (f32x2){selfm, selfm};

    const char* gb = (const char*)g;
    const unsigned int seg = ((unsigned int)s) << 4;

    for (int i = wave; i < N; i += nwaves) {
        int e0 = __builtin_amdgcn_readfirstlane(offsetsP[i]);
        int dg = __builtin_amdgcn_readfirstlane(deg[i]);
        int niter = (dg + 15) >> 4;

        uint4 us = *(const uint4*)(gb + (size_t)(((unsigned int)i << 7) | seg));
        f32x2 acc[4];
        acc[0] = selfv * (f32x2){u_lo(us.x), u_hi(us.x)};
        acc[1] = selfv * (f32x2){u_lo(us.y), u_hi(us.y)};
        acc[2] = selfv * (f32x2){u_lo(us.z), u_hi(us.z)};
        acc[3] = selfv * (f32x2){u_lo(us.w), u_hi(us.w)};

        const unsigned int* sp = srcsP + e0;
        for (int it = 0; it < niter; ++it) {
            unsigned int o0 = sp[grp];
            unsigned int o1 = sp[8 + grp];
            uint4 uA = *(const uint4*)(gb + (size_t)(o0 | seg));
            uint4 uB = *(const uint4*)(gb + (size_t)(o1 | seg));
            acc[0] += (f32x2){u_lo(uA.x), u_hi(uA.x)};
            acc[1] += (f32x2){u_lo(uA.y), u_hi(uA.y)};
            acc[2] += (f32x2){u_lo(uA.z), u_hi(uA.z)};
            acc[3] += (f32x2){u_lo(uA.w), u_hi(uA.w)};
            acc[0] += (f32x2){u_lo(uB.x), u_hi(uB.x)};
            acc[1] += (f32x2){u_lo(uB.y), u_hi(uB.y)};
            acc[2] += (f32x2){u_lo(uB.z), u_hi(uB.z)};
            acc[3] += (f32x2){u_lo(uB.w), u_hi(uB.w)};
            sp += 16;
        }

        #pragma unroll
        for (int m = 8; m <= 32; m <<= 1) {
            #pragma unroll
            for (int j = 0; j < 4; ++j) {
                f32x2 t = (f32x2){__shfl_xor(acc[j][0], m, 64),
                                  __shfl_xor(acc[j][1], m, 64)};
                acc[j] += t;
            }
        }

        float dinv = rsqrtf((float)dg + 1.0f);
        f32x2 dinv2 = (f32x2){dinv, dinv};
        f32x2 dot2 = (f32x2){0.f, 0.f};
        #pragma unroll
        for (int j = 0; j < 4; ++j) {
            f32x2 r = acc[j] * dinv2 + bb[j];
            r[0] = fmaxf(r[0], 0.f);
            r[1] = fmaxf(r[1], 0.f);
            dot2 += r * wl[j];
        }
        float t = dot2[0] + dot2[1];
        t += __shfl_xor(t, 1, 64);
        t += __shfl_xor(t, 2, 64);
        t += __shfl_xor(t, 4, 64);
        if (lane == 0)
            out[i] = 1.0f / (1.0f + expf(-(t + bl)));
    }
}

extern "C" void kernel_launch(void* const* d_in, const int* in_sizes, int n_in,
                              void* d_out, int out_size, void* d_ws, size_t ws_size,
                              hipStream_t stream) {
    const float* x      = (const float*)d_in[0];
    const int*   ei     = (const int*)d_in[1];
    const float* W_conv = (const float*)d_in[2];
    const float* b_conv = (const float*)d_in[3];
    const float* W_lin  = (const float*)d_in[4];
    const float* b_lin  = (const float*)d_in[5];

    const int N = in_sizes[0] / F_IN;     // 100000
    const int E = in_sizes[1] / 2;        // 1600000
    const int* src = ei;
    const int* dst = ei + E;
    float* out = (float*)d_out;

    const int NBC = (N + 255) >> 8;             // coarse buckets (391)
    const int NCH = (E + CHUNK - 1) / CHUNK;    // chunks (313)
    const int S   = NBC * NCH;                  // ~122k
    const int NB1 = (S + 255) / 256;            // scan groups (479) <= 512

    const int Na = (N + 256) & ~255;
    const int Sa = (S + 256) & ~255;
    const int Ea = (E + 255) & ~255;
    const int EPa = (E + NBC * PADSLACK + 511) & ~255;

    // workspace layout (4-byte units)
    int* M         = (int*)d_ws;                 // [Sa]
    int* tmp       = M + Sa;                     // [Sa]
    int* bsum      = tmp + Sa;                   // [512]
    int* offsetsP  = bsum + 512;                 // [Na]
    int* deg       = offsetsP + Na;              // [Na]
    unsigned short* Wbf = (unsigned short*)(deg + Na);        // [8192] bf16
    unsigned int* entries = (unsigned int*)(Wbf + 8192);      // [Ea]
    unsigned int* srcsP   = entries + Ea;        // [EPa]
    unsigned short* g = (unsigned short*)(srcsP + EPa);       // [(N+1)*64] bf16

    // cooperative partition kernel (one launch for the whole chain)
    int E_ = E, N_ = N, NBC_ = NBC, NCH_ = NCH, S_ = S, NB1_ = NB1;
    void* args[] = { (void*)&src, (void*)&dst, (void*)&E_,
                     (void*)&M, (void*)&tmp, (void*)&bsum,
                     (void*)&offsetsP, (void*)&deg,
                     (void*)&entries, (void*)&srcsP,
                     (void*)&N_, (void*)&NBC_, (void*)&NCH_, (void*)&S_, (void*)&NB1_,
                     (void*)&W_conv, (void*)&Wbf };
    hipLaunchCooperativeKernel((const void*)k_part, dim3(PART_GRID), dim3(256),
                               args, 0, stream);

    k_gemm<<<(N + 64) / 64, 256, 0, stream>>>(x, Wbf, deg, g, N);
    k_pull<<<4096, 256, 0, stream>>>(g, offsetsP, deg, srcsP, b_conv, W_lin, b_lin, out, N);
}

// Round 13
// 193.223 us; speedup vs baseline: 3.1889x; 3.1889x over previous
//
#include <hip/hip_runtime.h>
#include <hip/hip_bf16.h>
#include <math.h>

#define F_IN   128
#define F_OUT  64
#define CHUNK  5120          // edges per hist/scatter block
#define MAXB   512           // max coarse buckets
#define PADSLACK 4096        // per-bucket padded-window slack (256 dsts * 15 max pad)

typedef short bf16x8 __attribute__((ext_vector_type(8)));
typedef float f32x4  __attribute__((ext_vector_type(4)));

__device__ __forceinline__ float bf2f(unsigned short u) {
    union { unsigned int i; float f; } c; c.i = ((unsigned int)u) << 16; return c.f;
}
__device__ __forceinline__ unsigned short f2bf(float f) {
    union { float f; unsigned int i; } c; c.f = f;
    unsigned int r = c.i + 0x7FFFu + ((c.i >> 16) & 1u);   // RNE
    return (unsigned short)(r >> 16);
}
__device__ __forceinline__ unsigned int pk2bf(float a, float b) {
    __hip_bfloat162 p = __float22bfloat162_rn(make_float2(a, b));  // v_cvt_pk_bf16_f32
    union { __hip_bfloat162 h; unsigned int u; } c; c.h = p; return c.u;
}
__device__ __forceinline__ float u_lo(unsigned int u) {   // low bf16 -> f32: u<<16
    union { unsigned int i; float f; } c; c.i = u << 16; return c.f;
}
__device__ __forceinline__ float u_hi(unsigned int u) {   // high bf16 -> f32: u & 0xffff0000
    union { unsigned int i; float f; } c; c.i = u & 0xFFFF0000u; return c.f;
}

// ---- pass A: per-block coarse histogram [bucket][block] (LDS only) ----
__global__ __launch_bounds__(256) void k_hist(
    const int* __restrict__ dst, int E, int* __restrict__ M, int NBLK, int NBC) {
    __shared__ int hist[MAXB];
    for (int c = threadIdx.x; c < MAXB; c += 256) hist[c] = 0;
    __syncthreads();
    int e0 = blockIdx.x * CHUNK;
    int e1 = min(E, e0 + CHUNK);
    for (int e = e0 + threadIdx.x; e < e1; e += 256)
        atomicAdd(&hist[dst[e] >> 8], 1);
    __syncthreads();
    for (int c = threadIdx.x; c < NBC; c += 256)
        M[c * NBLK + blockIdx.x] = hist[c];
}

// ---- flat exclusive scan over S = NBC*NBLK elements (3 phases) ----
__global__ void k_scan1(const int* __restrict__ M, int* __restrict__ tmp,
                        int* __restrict__ bsum, int S) {
    __shared__ int sh[256];
    int i = blockIdx.x * 256 + threadIdx.x;
    int v = (i < S) ? M[i] : 0;
    sh[threadIdx.x] = v;
    __syncthreads();
    for (int off = 1; off < 256; off <<= 1) {
        int t = (threadIdx.x >= off) ? sh[threadIdx.x - off] : 0;
        __syncthreads();
        sh[threadIdx.x] += t;
        __syncthreads();
    }
    if (i < S) tmp[i] = sh[threadIdx.x];
    if (threadIdx.x == 255) bsum[blockIdx.x] = sh[255];
}

__global__ void k_scan2(int* __restrict__ bsum, int NB1) {
    __shared__ int sh[512];
    int v = (threadIdx.x < NB1) ? bsum[threadIdx.x] : 0;
    sh[threadIdx.x] = v;
    __syncthreads();
    for (int off = 1; off < 512; off <<= 1) {
        int t = (threadIdx.x >= off) ? sh[threadIdx.x - off] : 0;
        __syncthreads();
        sh[threadIdx.x] += t;
        __syncthreads();
    }
    if (threadIdx.x < NB1) bsum[threadIdx.x] = sh[threadIdx.x] - v;   // exclusive
}

// scan3: M <- exclusive scan; extract bucketOff[bucket]
__global__ void k_scan3(int* __restrict__ M, const int* __restrict__ tmp,
                        const int* __restrict__ bsum, int* __restrict__ bucketOff,
                        int S, int NBLK, int NBC, int E) {
    int i = blockIdx.x * 256 + threadIdx.x;
    if (i < S) {
        int orig = M[i];
        int o = tmp[i] - orig + bsum[blockIdx.x];
        M[i] = o;
        if (i % NBLK == 0) bucketOff[i / NBLK] = o;
    }
    if (i == 0) bucketOff[NBC] = E;
}

// ---- pass B: scatter packed entries (localdst<<24 | src) into coarse buckets ----
__global__ __launch_bounds__(256) void k_scatter(
    const int* __restrict__ src, const int* __restrict__ dst, int E,
    const int* __restrict__ M, int NBLK, int NBC, unsigned int* __restrict__ entries) {
    __shared__ int cur[MAXB];
    for (int c = threadIdx.x; c < NBC; c += 256)
        cur[c] = M[c * NBLK + blockIdx.x];
    __syncthreads();
    int e0 = blockIdx.x * CHUNK;
    int e1 = min(E, e0 + CHUNK);
    for (int e = e0 + threadIdx.x; e < e1; e += 256) {
        int d = dst[e];
        int s = src[e];
        int p = atomicAdd(&cur[d >> 8], 1);
        entries[p] = ((unsigned int)(d & 255) << 24) | (unsigned int)s;
    }
}

// ---- per-bucket counting sort -> PADDED global CSR of BYTE OFFSETS ----
// srcsP[p] = src<<7 (byte offset of g row). Lists padded to multiple of 16
// with sentinel N<<7 (g[N] is a zero row).
__global__ __launch_bounds__(256) void k_sort(
    const unsigned int* __restrict__ entries, const int* __restrict__ bucketOff,
    int* __restrict__ offsetsP, int* __restrict__ deg,
    unsigned int* __restrict__ srcsP, int N) {
    __shared__ int hist[256];
    __shared__ int curs[256];
    const int tid = threadIdx.x;
    const int b = blockIdx.x;
    const int start = bucketOff[b];
    const int end   = bucketOff[b + 1];
    const int startP = start + b * PADSLACK;

    hist[tid] = 0;
    __syncthreads();
    for (int i = start + tid; i < end; i += 256)
        atomicAdd(&hist[entries[i] >> 24], 1);
    __syncthreads();

    int cntv   = hist[tid];
    int padded = (cntv + 15) & ~15;        // 0 stays 0
    curs[tid] = padded;
    __syncthreads();
    for (int off = 1; off < 256; off <<= 1) {
        int t = (tid >= off) ? curs[tid - off] : 0;
        __syncthreads();
        curs[tid] += t;
        __syncthreads();
    }
    int exclP = curs[tid] - padded;
    int d = (b << 8) + tid;
    if (d < N) { offsetsP[d] = startP + exclP; deg[d] = cntv; }
    __syncthreads();
    curs[tid] = startP + exclP;            // scatter cursors
    __syncthreads();

    for (int i = start + tid; i < end; i += 256) {
        unsigned int v = entries[i];
        int p = atomicAdd(&curs[v >> 24], 1);
        srcsP[p] = (v & 0xFFFFFFu) << 7;   // byte offset
    }
    __syncthreads();

    // pad own dst's list with sentinel N<<7
    int padEnd = startP + exclP + padded;
    unsigned int sent = ((unsigned int)N) << 7;
    for (int p = curs[tid]; p < padEnd; ++p)
        srcsP[p] = sent;
}

// ---- MFMA GEMM: g = bf16( (x @ W^T) * rsqrt(deg[row]+1) ); g[N] = zero row ----
__global__ __launch_bounds__(256) void k_gemm(
    const float* __restrict__ x, const float* __restrict__ W,
    const int* __restrict__ deg, unsigned short* __restrict__ g, int N) {
    __shared__ unsigned short xs[64 * F_IN];     // 16 KB
    __shared__ unsigned short Wsh[F_OUT * F_IN]; // 16 KB
    __shared__ float dinvs[64];

    const int tid  = threadIdx.x;
    const int row0 = blockIdx.x * 64;

    {
        const float4* W4 = (const float4*)W;
        #pragma unroll
        for (int t = 0; t < 8; ++t) {
            int idx = t * 256 + tid;
            float4 v = W4[idx];
            uint2 u = make_uint2(pk2bf(v.x, v.y), pk2bf(v.z, v.w));
            *(uint2*)&Wsh[idx * 4] = u;
        }
    }
    {
        const float4* x4 = (const float4*)x;
        #pragma unroll
        for (int t = 0; t < 8; ++t) {
            int idx = t * 256 + tid;
            int r = idx >> 5;
            int grow = row0 + r;
            float4 v = make_float4(0.f, 0.f, 0.f, 0.f);
            if (grow < N) v = x4[(size_t)grow * 32 + (idx & 31)];
            uint2 u = make_uint2(pk2bf(v.x, v.y), pk2bf(v.z, v.w));
            *(uint2*)&xs[idx * 4] = u;
        }
    }
    if (tid < 64) {
        int grow = row0 + tid;
        float dv = 1.0f;
        if (grow < N) dv = rsqrtf((float)deg[grow] + 1.0f);
        dinvs[tid] = dv;
    }
    __syncthreads();

    const int lane = tid & 63;
    const int wave = tid >> 6;
    const int m = lane & 15;
    const int q = lane >> 4;
    const int r0 = wave * 16;

    bf16x8 a[4];
    #pragma unroll
    for (int ks = 0; ks < 4; ++ks)
        a[ks] = *(const bf16x8*)&xs[(r0 + m) * F_IN + ks * 32 + q * 8];

    f32x4 acc[4] = {{0,0,0,0},{0,0,0,0},{0,0,0,0},{0,0,0,0}};
    #pragma unroll
    for (int ct = 0; ct < 4; ++ct) {
        #pragma unroll
        for (int ks = 0; ks < 4; ++ks) {
            bf16x8 b = *(const bf16x8*)&Wsh[(ct * 16 + m) * F_IN + ks * 32 + q * 8];
            acc[ct] = __builtin_amdgcn_mfma_f32_16x16x32_bf16(a[ks], b, acc[ct], 0, 0, 0);
        }
    }

    float dv[4];
    #pragma unroll
    for (int reg = 0; reg < 4; ++reg)
        dv[reg] = dinvs[r0 + q * 4 + reg];
    #pragma unroll
    for (int ct = 0; ct < 4; ++ct) {
        #pragma unroll
        for (int reg = 0; reg < 4; ++reg) {
            int grow = row0 + r0 + q * 4 + reg;
            // grow == N writes the zero sentinel row (acc==0 there)
            if (grow <= N)
                g[(size_t)grow * F_OUT + ct * 16 + m] = f2bf(acc[ct][reg] * dv[reg]);
        }
    }
}

// ---- pull aggregation + fused epilogue: wave per dst, branchless MLP-8 loop ----
// srcsP holds byte offsets (src<<7). Lane's gather addr = g + (off | li<<2).
__global__ __launch_bounds__(256) void k_pull(
    const unsigned short* __restrict__ g, const int* __restrict__ offsetsP,
    const int* __restrict__ deg, const unsigned int* __restrict__ srcsP,
    const float* __restrict__ b_conv, const float* __restrict__ W_lin,
    const float* __restrict__ b_lin, float* __restrict__ out, int N) {
    const int lane   = threadIdx.x & 63;
    const int li     = lane & 31;
    const int half   = lane >> 5;
    const int wave   = (blockIdx.x * blockDim.x + threadIdx.x) >> 6;
    const int nwaves = (gridDim.x * blockDim.x) >> 6;

    const float2 wl = ((const float2*)W_lin)[li];
    const float2 bb = ((const float2*)b_conv)[li];
    const float  bl = b_lin[0];
    const char* gb = (const char*)g;
    const unsigned int lioff = ((unsigned int)li) << 2;

    for (int i = wave; i < N; i += nwaves) {
        int e0 = __builtin_amdgcn_readfirstlane(offsetsP[i]);
        int dg = __builtin_amdgcn_readfirstlane(deg[i]);
        int niter = (dg + 15) >> 4;

        // self loop: lower half only (upper half adds 0)
        unsigned int us = *(const unsigned int*)(gb + ((((unsigned int)i) << 7) | lioff));
        float2 acc;
        acc.x = half ? 0.f : u_lo(us);
        acc.y = half ? 0.f : u_hi(us);

        const unsigned int* sp = srcsP + e0 + half;   // lane's half-interleaved list
        for (int it = 0; it < niter; ++it) {
            unsigned int off[8];
            #pragma unroll
            for (int t = 0; t < 8; ++t)
                off[t] = sp[2 * t];                   // immediate offsets
            unsigned int u[8];
            #pragma unroll
            for (int t = 0; t < 8; ++t)
                u[t] = *(const unsigned int*)(gb + (size_t)(off[t] | lioff));
            #pragma unroll
            for (int t = 0; t < 8; ++t) {
                acc.x += u_lo(u[t]);
                acc.y += u_hi(u[t]);
            }
            sp += 16;
        }

        acc.x += __shfl_xor(acc.x, 32, 64);
        acc.y += __shfl_xor(acc.y, 32, 64);

        float dinv = rsqrtf((float)dg + 1.0f);
        float r0 = fmaxf(acc.x * dinv + bb.x, 0.f);
        float r1 = fmaxf(acc.y * dinv + bb.y, 0.f);
        float t = r0 * wl.x + r1 * wl.y;
        #pragma unroll
        for (int off = 32; off > 0; off >>= 1)
            t += __shfl_down(t, off, 64);
        if (lane == 0)
            out[i] = 1.0f / (1.0f + expf(-(0.5f * t + bl)));   // 0.5: features duplicated across halves
    }
}

extern "C" void kernel_launch(void* const* d_in, const int* in_sizes, int n_in,
                              void* d_out, int out_size, void* d_ws, size_t ws_size,
                              hipStream_t stream) {
    const float* x      = (const float*)d_in[0];
    const int*   ei     = (const int*)d_in[1];
    const float* W_conv = (const float*)d_in[2];
    const float* b_conv = (const float*)d_in[3];
    const float* W_lin  = (const float*)d_in[4];
    const float* b_lin  = (const float*)d_in[5];

    const int N = in_sizes[0] / F_IN;     // 100000
    const int E = in_sizes[1] / 2;        // 1600000
    const int* src = ei;
    const int* dst = ei + E;
    float* out = (float*)d_out;

    const int NBC  = (N + 255) >> 8;            // coarse buckets (391)
    const int NBLK = (E + CHUNK - 1) / CHUNK;   // hist/scatter blocks (313)
    const int S    = NBC * NBLK;                // ~122k
    const int NB1  = (S + 255) / 256;           // scan blocks (479) <= 512

    const int Na = (N + 256) & ~255;
    const int Sa = (S + 256) & ~255;
    const int Ea = (E + 255) & ~255;
    const int EPa = (E + NBC * PADSLACK + 511) & ~255;  // padded srcs size

    // workspace layout (4-byte units), ~34 MB total
    int* M         = (int*)d_ws;                 // [Sa]
    int* tmp       = M + Sa;                     // [Sa]
    int* bsum      = tmp + Sa;                   // [512]
    int* bucketOff = bsum + 512;                 // [MAXB+1]
    int* offsetsP  = bucketOff + (MAXB + 256);   // [Na]
    int* deg       = offsetsP + Na;              // [Na]
    unsigned int* entries = (unsigned int*)(deg + Na);        // [Ea]
    unsigned int* srcsP   = (unsigned int*)(entries + Ea);    // [EPa]
    unsigned short* g = (unsigned short*)(srcsP + EPa);       // [(N+1)*64] bf16

    k_hist   <<<NBLK, 256, 0, stream>>>(dst, E, M, NBLK, NBC);
    k_scan1  <<<NB1, 256, 0, stream>>>(M, tmp, bsum, S);
    k_scan2  <<<1, 512, 0, stream>>>(bsum, NB1);
    k_scan3  <<<NB1, 256, 0, stream>>>(M, tmp, bsum, bucketOff, S, NBLK, NBC, E);
    k_scatter<<<NBLK, 256, 0, stream>>>(src, dst, E, M, NBLK, NBC, entries);
    k_sort   <<<NBC, 256, 0, stream>>>(entries, bucketOff, offsetsP, deg, srcsP, N);
    k_gemm   <<<(N + 64) / 64, 256, 0, stream>>>(x, W_conv, deg, g, N);
    k_pull   <<<4096, 256, 0, stream>>>(g, offsetsP, deg, srcsP, b_conv, W_lin, b_lin, out, N);
}